// Round 6
// baseline (293.192 us; speedup 1.0000x reference)
//
#include <hip/hip_runtime.h>
#include <stdint.h>

typedef short short8 __attribute__((ext_vector_type(8)));
typedef float f32x4 __attribute__((ext_vector_type(4)));

#define TILE 128

__device__ __forceinline__ unsigned short f32_to_bf16(float f) {
    uint32_t u = __builtin_bit_cast(uint32_t, f);
    u += 0x7FFFu + ((u >> 16) & 1u);   // RNE; data has no NaNs
    return (unsigned short)(u >> 16);
}
__device__ __forceinline__ float bf16_to_f32(unsigned short h) {
    return __builtin_bit_cast(float, (uint32_t)h << 16);
}

// Prep: centers fp32 -> bf16 in MFMA fragment layout, cw[m] = {||c||^2 * q, alpha[m]},
// and zero the accumulators (loss, reg, block counter).
// Fragment layout: element (row R, k) -> Bp[(R/16)*2048 + (k/8)*128 + (R%16)*8 + (k%8)]
__global__ void prep_kernel(const float* __restrict__ C,
                            const float* __restrict__ alpha,
                            const float* __restrict__ sigma,
                            unsigned short* __restrict__ Bp,
                            float2* __restrict__ cw,
                            float* __restrict__ acc)
{
    const int t = threadIdx.x;
    const int g = blockIdx.x;          // 16-row group
    const int r = t >> 4;              // row within group
    const int c16 = t & 15;            // 8-elem k-chunk
    const int R = g * 16 + r;

    if (g == 0 && t == 0) {
        acc[0] = 0.f; acc[1] = 0.f;
        ((unsigned int*)acc)[2] = 0u;
    }

    const float4* src = (const float4*)(C + (size_t)R * 128 + c16 * 8);
    float4 va = src[0], vb = src[1];
    unsigned short h[8];
    h[0] = f32_to_bf16(va.x); h[1] = f32_to_bf16(va.y);
    h[2] = f32_to_bf16(va.z); h[3] = f32_to_bf16(va.w);
    h[4] = f32_to_bf16(vb.x); h[5] = f32_to_bf16(vb.y);
    h[6] = f32_to_bf16(vb.z); h[7] = f32_to_bf16(vb.w);
    float ss = 0.f;
    #pragma unroll
    for (int k = 0; k < 8; ++k) {
        float f = bf16_to_f32(h[k]);
        ss = fmaf(f, f, ss);
    }
    uint4 pk;
    pk.x = (uint32_t)h[0] | ((uint32_t)h[1] << 16);
    pk.y = (uint32_t)h[2] | ((uint32_t)h[3] << 16);
    pk.z = (uint32_t)h[4] | ((uint32_t)h[5] << 16);
    pk.w = (uint32_t)h[6] | ((uint32_t)h[7] << 16);
    *reinterpret_cast<uint4*>(Bp + (size_t)g * 2048 + c16 * 128 + r * 8) = pk;

    ss += __shfl_xor(ss, 1);
    ss += __shfl_xor(ss, 2);
    ss += __shfl_xor(ss, 4);
    ss += __shfl_xor(ss, 8);
    if (c16 == 0) {
        float sig = sigma[0];
        float q = 0.7213475204444817f / (sig * sig);  // log2(e)/(2 sigma^2)
        cw[R] = make_float2(ss * q, alpha[R]);
    }
}

// Fused: blocks [0,nA) = preds + loss-sum; blocks [nA,nA+nMt) = K_MM regularizer.
// A fragments hoisted into 64 regs once. B tiles staged into an LDS double
// buffer shared by all 4 waves (2x fewer vmem instrs/bytes through L1 vs
// per-wave global reads). Global prefetch of tile mt+1 issues right after
// the tile-mt barrier; first use (ds_write) is ~2000 cycles later, so L1/L2
// latency is fully hidden. One barrier per tile. Full exponent
// u = 2q*dot - q*x2 - q*c2 <= ~0 stays inside exp2 (factoring overflows on
// the K_MM diagonal — R3 NaN). Last block to finish assembles out[0].
__global__ __launch_bounds__(256, 2)
void fused_kernel(const float* __restrict__ X, int N,
                  const float* __restrict__ Yv,
                  const unsigned short* __restrict__ Bp,
                  const float2* __restrict__ cw,
                  const float* __restrict__ alpha,
                  const float* __restrict__ sigma,
                  const float* __restrict__ penalty,
                  int nA, int nMt, int nBlk,
                  float* __restrict__ preds_out,
                  float* __restrict__ out0,
                  float* __restrict__ acc)   // [0]=loss,[1]=reg,[2]=counter
{
    // ldsB[0] doubles as the A-staging buffer before the m-loop starts.
    __shared__ __align__(16) unsigned short ldsB[2][16384];  // 2 x 32 KB
    __shared__ float a2p[TILE][2];
    __shared__ float predbuf[TILE][2];

    const int t    = threadIdx.x;
    const int lane = t & 63;
    const int wid  = t >> 6;
    const int wr   = wid >> 1;
    const int wc   = wid & 1;
    const int l15  = lane & 15;
    const int quad = lane >> 4;

    const float sig = sigma[0];
    const float q  = 0.7213475204444817f / (sig * sig);
    const float q2 = 2.0f * q;

    const bool regmode = (int)blockIdx.x >= nA;
    int rowbase;
    float rowterm[4][4];
    short8 a[16];   // A fragments, tile-invariant: a[i*4+kk]

    if (!regmode) {
        rowbase = blockIdx.x * TILE;
        const int r_   = t >> 1;
        const int half = t & 1;
        const int grow = rowbase + r_;
        unsigned short* dstbase = &ldsB[0][0] + (r_ >> 4) * 2048 + (r_ & 15) * 8;
        float ss = 0.f;
        if (grow < N) {
            const float4* src = (const float4*)(X + (size_t)grow * 128 + half * 64);
            #pragma unroll
            for (int c = 0; c < 8; ++c) {
                float4 va = src[2 * c], vb = src[2 * c + 1];
                unsigned short h0 = f32_to_bf16(va.x), h1 = f32_to_bf16(va.y);
                unsigned short h2 = f32_to_bf16(va.z), h3 = f32_to_bf16(va.w);
                unsigned short h4 = f32_to_bf16(vb.x), h5 = f32_to_bf16(vb.y);
                unsigned short h6 = f32_to_bf16(vb.z), h7 = f32_to_bf16(vb.w);
                float f0 = bf16_to_f32(h0), f1 = bf16_to_f32(h1);
                float f2 = bf16_to_f32(h2), f3 = bf16_to_f32(h3);
                float f4 = bf16_to_f32(h4), f5 = bf16_to_f32(h5);
                float f6 = bf16_to_f32(h6), f7 = bf16_to_f32(h7);
                ss = fmaf(f0, f0, ss); ss = fmaf(f1, f1, ss);
                ss = fmaf(f2, f2, ss); ss = fmaf(f3, f3, ss);
                ss = fmaf(f4, f4, ss); ss = fmaf(f5, f5, ss);
                ss = fmaf(f6, f6, ss); ss = fmaf(f7, f7, ss);
                uint4 pk;
                pk.x = (uint32_t)h0 | ((uint32_t)h1 << 16);
                pk.y = (uint32_t)h2 | ((uint32_t)h3 << 16);
                pk.z = (uint32_t)h4 | ((uint32_t)h5 << 16);
                pk.w = (uint32_t)h6 | ((uint32_t)h7 << 16);
                *reinterpret_cast<uint4*>(dstbase + (half * 8 + c) * 128) = pk;
            }
        } else {
            uint4 z; z.x = z.y = z.z = z.w = 0u;
            #pragma unroll
            for (int c = 0; c < 8; ++c)
                *reinterpret_cast<uint4*>(dstbase + (half * 8 + c) * 128) = z;
        }
        a2p[r_][half] = ss;
        __syncthreads();
        #pragma unroll
        for (int i = 0; i < 4; ++i)
            #pragma unroll
            for (int r = 0; r < 4; ++r) {
                int rl = wr * 64 + i * 16 + quad * 4 + r;
                rowterm[i][r] = (a2p[rl][0] + a2p[rl][1]) * q;
            }
        // hoist A fragments: 16 ds_read_b128, once for the whole kernel
        const unsigned short* aLds = &ldsB[0][0] + (size_t)(wr * 4) * 2048 + lane * 8;
        #pragma unroll
        for (int i = 0; i < 4; ++i)
            #pragma unroll
            for (int kk = 0; kk < 4; ++kk)
                a[i * 4 + kk] = *reinterpret_cast<const short8*>(aLds + (size_t)i * 2048 + kk * 512);
    } else {
        const int b2 = (int)blockIdx.x - nA;
        rowbase = b2 * TILE;
        const unsigned short* aG = Bp + (size_t)(b2 * 8 + wr * 4) * 2048 + lane * 8;
        #pragma unroll
        for (int i = 0; i < 4; ++i)
            #pragma unroll
            for (int kk = 0; kk < 4; ++kk)
                a[i * 4 + kk] = *reinterpret_cast<const short8*>(aG + (size_t)i * 2048 + kk * 512);
        #pragma unroll
        for (int i = 0; i < 4; ++i)
            #pragma unroll
            for (int r = 0; r < 4; ++r)
                rowterm[i][r] = cw[rowbase + wr * 64 + i * 16 + quad * 4 + r].x;
        __syncthreads();   // keep barrier count aligned with mode-0 path
    }

    float srow[4][4] = {};
    const float2* cwb = cw + wc * 64 + l15;

    // staging id: this wave stages quarter `wid` of each tile (uint4 units)
    const int sbase = wid * 512 + lane;

    // prefetch tile 0 (global -> regs) + its column constants
    uint4 st[8];
    {
        const uint4* src = (const uint4*)Bp;
        #pragma unroll
        for (int k = 0; k < 8; ++k) st[k] = src[sbase + k * 64];
    }
    float2 cj[4], cjn[4];
    #pragma unroll
    for (int j = 0; j < 4; ++j) cj[j] = cwb[j * 16];

    __syncthreads();   // mode-0: all waves done reading A from ldsB[0]

    // write tile 0 into ldsB[0]
    {
        uint4* dst = (uint4*)&ldsB[0][0];
        #pragma unroll
        for (int k = 0; k < 8; ++k) dst[sbase + k * 64] = st[k];
    }

    for (int mt = 0; mt < nMt; ++mt) {
        __syncthreads();   // tile mt resident in ldsB[mt&1]; prev readers done
        const unsigned short* buf = &ldsB[mt & 1][0];

        const bool more = (mt + 1 < nMt);
        if (more) {
            // global prefetch of tile mt+1 — first use is the ds_write below,
            // ~2000 cycles away: latency fully hidden
            const uint4* src = (const uint4*)Bp + (size_t)(mt + 1) * 2048;
            #pragma unroll
            for (int k = 0; k < 8; ++k) st[k] = src[sbase + k * 64];
            #pragma unroll
            for (int j = 0; j < 4; ++j) cjn[j] = cwb[(size_t)(mt + 1) * 128 + j * 16];
        }

        // compute: 4 column groups of 16, K=128 each
        const unsigned short* bfr = buf + (size_t)(wc * 4) * 2048 + lane * 8;
        #pragma unroll
        for (int j = 0; j < 4; ++j) {
            short8 b[4];
            #pragma unroll
            for (int kk = 0; kk < 4; ++kk)
                b[kk] = *reinterpret_cast<const short8*>(bfr + (size_t)j * 2048 + kk * 512);

            f32x4 acc4[4];
            #pragma unroll
            for (int i = 0; i < 4; ++i) acc4[i] = (f32x4){0.f, 0.f, 0.f, 0.f};
            #pragma unroll
            for (int kk = 0; kk < 4; ++kk)
                #pragma unroll
                for (int i = 0; i < 4; ++i)
                    acc4[i] = __builtin_amdgcn_mfma_f32_16x16x32_bf16(
                        a[i * 4 + kk], b[kk], acc4[i], 0, 0, 0);

            // epilogue: u = 2q*dot - (q*x2 + q*c2) <= ~0 ; srow += exp2(u)*alpha
            #pragma unroll
            for (int i = 0; i < 4; ++i) {
                #pragma unroll
                for (int r = 0; r < 4; ++r) {
                    float u = fmaf(acc4[i][r], q2, -(rowterm[i][r] + cj[j].x));
                    float e = __builtin_amdgcn_exp2f(u);
                    srow[i][r] = fmaf(e, cj[j].y, srow[i][r]);
                }
            }
        }

        if (more) {
            uint4* dst = (uint4*)&ldsB[(mt + 1) & 1][0];
            #pragma unroll
            for (int k = 0; k < 8; ++k) dst[sbase + k * 64] = st[k];
            #pragma unroll
            for (int j = 0; j < 4; ++j) cj[j] = cjn[j];
        }
    }

    // reduce srow over the 16 lanes sharing a row
    #pragma unroll
    for (int i = 0; i < 4; ++i) {
        #pragma unroll
        for (int r = 0; r < 4; ++r) {
            int rl = wr * 64 + i * 16 + quad * 4 + r;
            float v = srow[i][r];
            v += __shfl_xor(v, 1);
            v += __shfl_xor(v, 2);
            v += __shfl_xor(v, 4);
            v += __shfl_xor(v, 8);
            if (l15 == 0)
                predbuf[rl][wc] = v;
        }
    }
    __syncthreads();

    float contrib = 0.f;
    if (t < TILE) {
        int grow = rowbase + t;
        if (!regmode) {
            if (grow < N) {
                float pred = predbuf[t][0] + predbuf[t][1];
                preds_out[grow] = pred;
                float d = pred - Yv[grow];
                contrib = d * d;
            }
        } else {
            float pred = predbuf[t][0] + predbuf[t][1];
            contrib = alpha[grow] * pred;
        }
    }
    contrib += __shfl_xor(contrib, 1);
    contrib += __shfl_xor(contrib, 2);
    contrib += __shfl_xor(contrib, 4);
    contrib += __shfl_xor(contrib, 8);
    contrib += __shfl_xor(contrib, 16);
    contrib += __shfl_xor(contrib, 32);
    if (lane == 0) atomicAdd(regmode ? (acc + 1) : (acc + 0), contrib);

    __syncthreads();   // all 4 waves' atomics drained before counting
    if (t == 0) {
        __threadfence();
        unsigned int old = atomicAdd((unsigned int*)(acc + 2), 1u);
        if (old == (unsigned int)(nBlk - 1)) {
            float lv = atomicAdd(acc + 0, 0.0f);   // coherent read-back
            float rv = atomicAdd(acc + 1, 0.0f);
            out0[0] = lv / (float)N + __expf(-penalty[0]) * rv;
        }
    }
}

extern "C" void kernel_launch(void* const* d_in, const int* in_sizes, int n_in,
                              void* d_out, int out_size, void* d_ws, size_t ws_size,
                              hipStream_t stream) {
    const float* X       = (const float*)d_in[0];
    const float* Y       = (const float*)d_in[1];
    const float* centers = (const float*)d_in[2];
    const float* alpha   = (const float*)d_in[3];
    const float* sigma   = (const float*)d_in[4];
    const float* penalty = (const float*)d_in[5];
    float* out = (float*)d_out;

    const int N = in_sizes[1];   // Y is [N,1]
    const int M = in_sizes[3];   // alpha is [M,1]

    unsigned short* Bp = (unsigned short*)d_ws;                 // M*128 bf16 = M*256 B
    float2* cw = (float2*)((char*)d_ws + (size_t)M * 256);      // M*8 B
    float* acc = (float*)((char*)d_ws + (size_t)M * 264);       // loss, reg, counter

    prep_kernel<<<M / 16, 256, 0, stream>>>(centers, alpha, sigma, Bp, cw, acc);

    const int nA  = (N + TILE - 1) / TILE;
    const int nMt = M / TILE;
    const int nBlk = nA + nMt;
    fused_kernel<<<nBlk, 256, 0, stream>>>(X, N, Y, Bp, cw, alpha, sigma, penalty,
                                           nA, nMt, nBlk, out + 1, out, acc);
}

// Round 7
// 207.981 us; speedup vs baseline: 1.4097x; 1.4097x over previous
//
#include <hip/hip_runtime.h>
#include <stdint.h>

typedef short short8 __attribute__((ext_vector_type(8)));
typedef float f32x4 __attribute__((ext_vector_type(4)));

#define TILE 128

__device__ __forceinline__ unsigned short f32_to_bf16(float f) {
    uint32_t u = __builtin_bit_cast(uint32_t, f);
    u += 0x7FFFu + ((u >> 16) & 1u);   // RNE; data has no NaNs
    return (unsigned short)(u >> 16);
}
__device__ __forceinline__ float bf16_to_f32(unsigned short h) {
    return __builtin_bit_cast(float, (uint32_t)h << 16);
}

// async global->LDS DMA, 16 B per lane per issue (global_load_lds_dwordx4).
// HW semantics: per-lane global address; LDS dest = wave-uniform base + lane*16.
typedef const __attribute__((address_space(1))) uint32_t guint;
typedef __attribute__((address_space(3))) uint32_t luint;
__device__ __forceinline__ void dma16(const void* g, void* l) {
    __builtin_amdgcn_global_load_lds((guint*)g, (luint*)l, 16, 0, 0);
}

// Prep: centers fp32 -> bf16 in MFMA fragment layout, cw[m] = {||c||^2 * q, alpha[m]},
// and zero the accumulators (loss, reg, block counter).
// Fragment layout: element (row R, k) -> Bp[(R/16)*2048 + (k/8)*128 + (R%16)*8 + (k%8)]
__global__ void prep_kernel(const float* __restrict__ C,
                            const float* __restrict__ alpha,
                            const float* __restrict__ sigma,
                            unsigned short* __restrict__ Bp,
                            float2* __restrict__ cw,
                            float* __restrict__ acc)
{
    const int t = threadIdx.x;
    const int g = blockIdx.x;          // 16-row group
    const int r = t >> 4;              // row within group
    const int c16 = t & 15;            // 8-elem k-chunk
    const int R = g * 16 + r;

    if (g == 0 && t == 0) {
        acc[0] = 0.f; acc[1] = 0.f;
        ((unsigned int*)acc)[2] = 0u;
    }

    const float4* src = (const float4*)(C + (size_t)R * 128 + c16 * 8);
    float4 va = src[0], vb = src[1];
    unsigned short h[8];
    h[0] = f32_to_bf16(va.x); h[1] = f32_to_bf16(va.y);
    h[2] = f32_to_bf16(va.z); h[3] = f32_to_bf16(va.w);
    h[4] = f32_to_bf16(vb.x); h[5] = f32_to_bf16(vb.y);
    h[6] = f32_to_bf16(vb.z); h[7] = f32_to_bf16(vb.w);
    float ss = 0.f;
    #pragma unroll
    for (int k = 0; k < 8; ++k) {
        float f = bf16_to_f32(h[k]);
        ss = fmaf(f, f, ss);
    }
    uint4 pk;
    pk.x = (uint32_t)h[0] | ((uint32_t)h[1] << 16);
    pk.y = (uint32_t)h[2] | ((uint32_t)h[3] << 16);
    pk.z = (uint32_t)h[4] | ((uint32_t)h[5] << 16);
    pk.w = (uint32_t)h[6] | ((uint32_t)h[7] << 16);
    *reinterpret_cast<uint4*>(Bp + (size_t)g * 2048 + c16 * 128 + r * 8) = pk;

    ss += __shfl_xor(ss, 1);
    ss += __shfl_xor(ss, 2);
    ss += __shfl_xor(ss, 4);
    ss += __shfl_xor(ss, 8);
    if (c16 == 0) {
        float sig = sigma[0];
        float q = 0.7213475204444817f / (sig * sig);  // log2(e)/(2 sigma^2)
        cw[R] = make_float2(ss * q, alpha[R]);
    }
}

// Fused: blocks [0,nA) = preds + loss-sum; blocks [nA,nA+nMt) = K_MM regularizer.
// m97 structure: B tiles staged by async DMA (global_load_lds_dwordx4, zero
// VGPR cost — manual reg staging spilled in R4/R6) into a 2x32KB LDS double
// buffer. DMA for tile mt+1 fires at loop top; __syncthreads' vmcnt-drain at
// tile end lands after ~1500cyc of compute, amortizing L3/HBM latency.
// A fragments hoisted into 64 regs once. Full exponent
// u = 2q*dot - q*x2 - q*c2 <= ~0 stays inside exp2 (factoring overflows on
// the K_MM diagonal — R3 NaN). Last block to finish assembles out[0].
__global__ __launch_bounds__(256, 2)
void fused_kernel(const float* __restrict__ X, int N,
                  const float* __restrict__ Yv,
                  const unsigned short* __restrict__ Bp,
                  const float2* __restrict__ cw,
                  const float* __restrict__ alpha,
                  const float* __restrict__ sigma,
                  const float* __restrict__ penalty,
                  int nA, int nMt, int nBlk,
                  float* __restrict__ preds_out,
                  float* __restrict__ out0,
                  float* __restrict__ acc)   // [0]=loss,[1]=reg,[2]=counter
{
    // ldsB[0] doubles as the A-staging buffer before the m-loop starts.
    __shared__ __align__(16) unsigned short ldsB[2][16384];  // 2 x 32 KB
    __shared__ float a2p[TILE][2];
    __shared__ float predbuf[TILE][2];

    const int t    = threadIdx.x;
    const int lane = t & 63;
    const int wid  = t >> 6;
    const int wr   = wid >> 1;
    const int wc   = wid & 1;
    const int l15  = lane & 15;
    const int quad = lane >> 4;

    const float sig = sigma[0];
    const float q  = 0.7213475204444817f / (sig * sig);
    const float q2 = 2.0f * q;

    const bool regmode = (int)blockIdx.x >= nA;
    int rowbase;
    float rowterm[4][4];
    short8 a[16];   // A fragments, tile-invariant: a[i*4+kk]

    if (!regmode) {
        rowbase = blockIdx.x * TILE;
        const int r_   = t >> 1;
        const int half = t & 1;
        const int grow = rowbase + r_;
        unsigned short* dstbase = &ldsB[0][0] + (r_ >> 4) * 2048 + (r_ & 15) * 8;
        float ss = 0.f;
        if (grow < N) {
            const float4* src = (const float4*)(X + (size_t)grow * 128 + half * 64);
            #pragma unroll
            for (int c = 0; c < 8; ++c) {
                float4 va = src[2 * c], vb = src[2 * c + 1];
                unsigned short h0 = f32_to_bf16(va.x), h1 = f32_to_bf16(va.y);
                unsigned short h2 = f32_to_bf16(va.z), h3 = f32_to_bf16(va.w);
                unsigned short h4 = f32_to_bf16(vb.x), h5 = f32_to_bf16(vb.y);
                unsigned short h6 = f32_to_bf16(vb.z), h7 = f32_to_bf16(vb.w);
                float f0 = bf16_to_f32(h0), f1 = bf16_to_f32(h1);
                float f2 = bf16_to_f32(h2), f3 = bf16_to_f32(h3);
                float f4 = bf16_to_f32(h4), f5 = bf16_to_f32(h5);
                float f6 = bf16_to_f32(h6), f7 = bf16_to_f32(h7);
                ss = fmaf(f0, f0, ss); ss = fmaf(f1, f1, ss);
                ss = fmaf(f2, f2, ss); ss = fmaf(f3, f3, ss);
                ss = fmaf(f4, f4, ss); ss = fmaf(f5, f5, ss);
                ss = fmaf(f6, f6, ss); ss = fmaf(f7, f7, ss);
                uint4 pk;
                pk.x = (uint32_t)h0 | ((uint32_t)h1 << 16);
                pk.y = (uint32_t)h2 | ((uint32_t)h3 << 16);
                pk.z = (uint32_t)h4 | ((uint32_t)h5 << 16);
                pk.w = (uint32_t)h6 | ((uint32_t)h7 << 16);
                *reinterpret_cast<uint4*>(dstbase + (half * 8 + c) * 128) = pk;
            }
        } else {
            uint4 z; z.x = z.y = z.z = z.w = 0u;
            #pragma unroll
            for (int c = 0; c < 8; ++c)
                *reinterpret_cast<uint4*>(dstbase + (half * 8 + c) * 128) = z;
        }
        a2p[r_][half] = ss;
        __syncthreads();
        #pragma unroll
        for (int i = 0; i < 4; ++i)
            #pragma unroll
            for (int r = 0; r < 4; ++r) {
                int rl = wr * 64 + i * 16 + quad * 4 + r;
                rowterm[i][r] = (a2p[rl][0] + a2p[rl][1]) * q;
            }
        // hoist A fragments: 16 ds_read_b128, once for the whole kernel
        const unsigned short* aLds = &ldsB[0][0] + (size_t)(wr * 4) * 2048 + lane * 8;
        #pragma unroll
        for (int i = 0; i < 4; ++i)
            #pragma unroll
            for (int kk = 0; kk < 4; ++kk)
                a[i * 4 + kk] = *reinterpret_cast<const short8*>(aLds + (size_t)i * 2048 + kk * 512);
        __syncthreads();   // all waves done reading A from ldsB[0] before DMA overwrites
    } else {
        const int b2 = (int)blockIdx.x - nA;
        rowbase = b2 * TILE;
        const unsigned short* aG = Bp + (size_t)(b2 * 8 + wr * 4) * 2048 + lane * 8;
        #pragma unroll
        for (int i = 0; i < 4; ++i)
            #pragma unroll
            for (int kk = 0; kk < 4; ++kk)
                a[i * 4 + kk] = *reinterpret_cast<const short8*>(aG + (size_t)i * 2048 + kk * 512);
        #pragma unroll
        for (int i = 0; i < 4; ++i)
            #pragma unroll
            for (int r = 0; r < 4; ++r)
                rowterm[i][r] = cw[rowbase + wr * 64 + i * 16 + quad * 4 + r].x;
    }

    float srow[4][4] = {};
    const float2* cwb = cw + wc * 64 + l15;

    // this wave stages its 8 KB quarter of each tile: 8 x 1KB DMA issues
    const int ldq = wid * 4096 + lane * 8;   // element offset (shorts)

    // DMA tile 0 into ldsB[0] + prefetch its column constants
    {
        const unsigned short* g = Bp + ldq;
        unsigned short* l = &ldsB[0][0] + ldq;
        #pragma unroll
        for (int k = 0; k < 8; ++k)
            dma16(g + k * 512, l + k * 512);
    }
    float2 cj[4], cjn[4];
    #pragma unroll
    for (int j = 0; j < 4; ++j) cj[j] = cwb[j * 16];

    __syncthreads();   // vmcnt drain: tile 0 resident

    for (int mt = 0; mt < nMt; ++mt) {
        const bool more = (mt + 1 < nMt);
        if (more) {
            // fire-and-forget DMA of tile mt+1 into the other buffer;
            // drained by the barrier at the END of this iteration.
            const unsigned short* g = Bp + (size_t)(mt + 1) * 16384 + ldq;
            unsigned short* l = &ldsB[(mt + 1) & 1][0] + ldq;
            #pragma unroll
            for (int k = 0; k < 8; ++k)
                dma16(g + k * 512, l + k * 512);
            #pragma unroll
            for (int j = 0; j < 4; ++j) cjn[j] = cwb[(size_t)(mt + 1) * 128 + j * 16];
        }

        // compute tile mt from LDS: 4 column groups of 16, K=128 each
        const unsigned short* bfr = &ldsB[mt & 1][0] + (size_t)(wc * 4) * 2048 + lane * 8;
        #pragma unroll
        for (int j = 0; j < 4; ++j) {
            short8 b[4];
            #pragma unroll
            for (int kk = 0; kk < 4; ++kk)
                b[kk] = *reinterpret_cast<const short8*>(bfr + (size_t)j * 2048 + kk * 512);

            f32x4 acc4[4];
            #pragma unroll
            for (int i = 0; i < 4; ++i) acc4[i] = (f32x4){0.f, 0.f, 0.f, 0.f};
            #pragma unroll
            for (int kk = 0; kk < 4; ++kk)
                #pragma unroll
                for (int i = 0; i < 4; ++i)
                    acc4[i] = __builtin_amdgcn_mfma_f32_16x16x32_bf16(
                        a[i * 4 + kk], b[kk], acc4[i], 0, 0, 0);

            // epilogue: u = 2q*dot - (q*x2 + q*c2) <= ~0 ; srow += exp2(u)*alpha
            #pragma unroll
            for (int i = 0; i < 4; ++i) {
                #pragma unroll
                for (int r = 0; r < 4; ++r) {
                    float u = fmaf(acc4[i][r], q2, -(rowterm[i][r] + cj[j].x));
                    float e = __builtin_amdgcn_exp2f(u);
                    srow[i][r] = fmaf(e, cj[j].y, srow[i][r]);
                }
            }
        }

        __syncthreads();   // drains DMA(mt+1); all waves done reading buf[mt&1]
        if (more) {
            #pragma unroll
            for (int j = 0; j < 4; ++j) cj[j] = cjn[j];
        }
    }

    // reduce srow over the 16 lanes sharing a row
    #pragma unroll
    for (int i = 0; i < 4; ++i) {
        #pragma unroll
        for (int r = 0; r < 4; ++r) {
            int rl = wr * 64 + i * 16 + quad * 4 + r;
            float v = srow[i][r];
            v += __shfl_xor(v, 1);
            v += __shfl_xor(v, 2);
            v += __shfl_xor(v, 4);
            v += __shfl_xor(v, 8);
            if (l15 == 0)
                predbuf[rl][wc] = v;
        }
    }
    __syncthreads();

    float contrib = 0.f;
    if (t < TILE) {
        int grow = rowbase + t;
        if (!regmode) {
            if (grow < N) {
                float pred = predbuf[t][0] + predbuf[t][1];
                preds_out[grow] = pred;
                float d = pred - Yv[grow];
                contrib = d * d;
            }
        } else {
            float pred = predbuf[t][0] + predbuf[t][1];
            contrib = alpha[grow] * pred;
        }
    }
    contrib += __shfl_xor(contrib, 1);
    contrib += __shfl_xor(contrib, 2);
    contrib += __shfl_xor(contrib, 4);
    contrib += __shfl_xor(contrib, 8);
    contrib += __shfl_xor(contrib, 16);
    contrib += __shfl_xor(contrib, 32);
    if (lane == 0) atomicAdd(regmode ? (acc + 1) : (acc + 0), contrib);

    __syncthreads();   // all 4 waves' atomics drained before counting
    if (t == 0) {
        __threadfence();
        unsigned int old = atomicAdd((unsigned int*)(acc + 2), 1u);
        if (old == (unsigned int)(nBlk - 1)) {
            float lv = atomicAdd(acc + 0, 0.0f);   // coherent read-back
            float rv = atomicAdd(acc + 1, 0.0f);
            out0[0] = lv / (float)N + __expf(-penalty[0]) * rv;
        }
    }
}

extern "C" void kernel_launch(void* const* d_in, const int* in_sizes, int n_in,
                              void* d_out, int out_size, void* d_ws, size_t ws_size,
                              hipStream_t stream) {
    const float* X       = (const float*)d_in[0];
    const float* Y       = (const float*)d_in[1];
    const float* centers = (const float*)d_in[2];
    const float* alpha   = (const float*)d_in[3];
    const float* sigma   = (const float*)d_in[4];
    const float* penalty = (const float*)d_in[5];
    float* out = (float*)d_out;

    const int N = in_sizes[1];   // Y is [N,1]
    const int M = in_sizes[3];   // alpha is [M,1]

    unsigned short* Bp = (unsigned short*)d_ws;                 // M*128 bf16 = M*256 B
    float2* cw = (float2*)((char*)d_ws + (size_t)M * 256);      // M*8 B
    float* acc = (float*)((char*)d_ws + (size_t)M * 264);       // loss, reg, counter

    prep_kernel<<<M / 16, 256, 0, stream>>>(centers, alpha, sigma, Bp, cw, acc);

    const int nA  = (N + TILE - 1) / TILE;
    const int nMt = M / TILE;
    const int nBlk = nA + nMt;
    fused_kernel<<<nBlk, 256, 0, stream>>>(X, N, Y, Bp, cw, alpha, sigma, penalty,
                                           nA, nMt, nBlk, out + 1, out, acc);
}

// Round 8
// 182.735 us; speedup vs baseline: 1.6045x; 1.1382x over previous
//
#include <hip/hip_runtime.h>
#include <stdint.h>

typedef short short8 __attribute__((ext_vector_type(8)));
typedef float f32x4 __attribute__((ext_vector_type(4)));

#define TILE 128

__device__ __forceinline__ unsigned short f32_to_bf16(float f) {
    uint32_t u = __builtin_bit_cast(uint32_t, f);
    u += 0x7FFFu + ((u >> 16) & 1u);   // RNE; data has no NaNs
    return (unsigned short)(u >> 16);
}
__device__ __forceinline__ float bf16_to_f32(unsigned short h) {
    return __builtin_bit_cast(float, (uint32_t)h << 16);
}

// async global->LDS DMA, 16 B per lane per issue (global_load_lds_dwordx4).
// HW semantics: per-lane global address; LDS dest = wave-uniform base + lane*16.
typedef const __attribute__((address_space(1))) uint32_t guint;
typedef __attribute__((address_space(3))) uint32_t luint;
__device__ __forceinline__ void dma16(const void* g, void* l) {
    __builtin_amdgcn_global_load_lds((guint*)g, (luint*)l, 16, 0, 0);
}

// Prep: centers fp32 -> bf16 in MFMA fragment layout, cw[m] = {||c||^2 * q, alpha[m]},
// and zero the accumulators (loss, reg, block counter).
// Fragment layout: element (row R, k) -> Bp[(R/16)*2048 + (k/8)*128 + (R%16)*8 + (k%8)]
__global__ void prep_kernel(const float* __restrict__ C,
                            const float* __restrict__ alpha,
                            const float* __restrict__ sigma,
                            unsigned short* __restrict__ Bp,
                            float2* __restrict__ cw,
                            float* __restrict__ acc)
{
    const int t = threadIdx.x;
    const int g = blockIdx.x;          // 16-row group
    const int r = t >> 4;              // row within group
    const int c16 = t & 15;            // 8-elem k-chunk
    const int R = g * 16 + r;

    if (g == 0 && t == 0) {
        acc[0] = 0.f; acc[1] = 0.f;
        ((unsigned int*)acc)[2] = 0u;
    }

    const float4* src = (const float4*)(C + (size_t)R * 128 + c16 * 8);
    float4 va = src[0], vb = src[1];
    unsigned short h[8];
    h[0] = f32_to_bf16(va.x); h[1] = f32_to_bf16(va.y);
    h[2] = f32_to_bf16(va.z); h[3] = f32_to_bf16(va.w);
    h[4] = f32_to_bf16(vb.x); h[5] = f32_to_bf16(vb.y);
    h[6] = f32_to_bf16(vb.z); h[7] = f32_to_bf16(vb.w);
    float ss = 0.f;
    #pragma unroll
    for (int k = 0; k < 8; ++k) {
        float f = bf16_to_f32(h[k]);
        ss = fmaf(f, f, ss);
    }
    uint4 pk;
    pk.x = (uint32_t)h[0] | ((uint32_t)h[1] << 16);
    pk.y = (uint32_t)h[2] | ((uint32_t)h[3] << 16);
    pk.z = (uint32_t)h[4] | ((uint32_t)h[5] << 16);
    pk.w = (uint32_t)h[6] | ((uint32_t)h[7] << 16);
    *reinterpret_cast<uint4*>(Bp + (size_t)g * 2048 + c16 * 128 + r * 8) = pk;

    ss += __shfl_xor(ss, 1);
    ss += __shfl_xor(ss, 2);
    ss += __shfl_xor(ss, 4);
    ss += __shfl_xor(ss, 8);
    if (c16 == 0) {
        float sig = sigma[0];
        float q = 0.7213475204444817f / (sig * sig);  // log2(e)/(2 sigma^2)
        cw[R] = make_float2(ss * q, alpha[R]);
    }
}

// Fused: blocks [0,nA) = preds + loss-sum; blocks [nA,nA+nMt) = K_MM regularizer.
// 512 threads = 8 waves in a 4(row)x2(col) grid; each wave owns 32 rows x 64
// cols of the 128x128 tile. Halves per-wave register demand (a[8] = 32 regs)
// so __launch_bounds__(512,4) caps at 128 VGPR -> 4 waves/SIMD (2 blocks/CU)
// = 2x the TLP of the 256-thread version, whose 1.2-1.6 waves/SIMD left every
// latency exposed (R2/R5/R7 all ~130us regardless of staging scheme).
// B tiles staged by async DMA into 2x32KB LDS double buffer (zero VGPR cost —
// manual reg staging spilled in R4/R6). Full exponent u = 2q*dot - q*x2 - q*c2
// <= ~0 stays inside exp2 (factoring overflows on the K_MM diagonal — R3 NaN).
// Last block to finish assembles out[0].
__global__ __launch_bounds__(512, 4)
void fused_kernel(const float* __restrict__ X, int N,
                  const float* __restrict__ Yv,
                  const unsigned short* __restrict__ Bp,
                  const float2* __restrict__ cw,
                  const float* __restrict__ alpha,
                  const float* __restrict__ sigma,
                  const float* __restrict__ penalty,
                  int nA, int nMt, int nBlk,
                  float* __restrict__ preds_out,
                  float* __restrict__ out0,
                  float* __restrict__ acc)   // [0]=loss,[1]=reg,[2]=counter
{
    // ldsB[0] doubles as the A-staging buffer before the m-loop starts.
    __shared__ __align__(16) unsigned short ldsB[2][16384];  // 2 x 32 KB
    __shared__ float a2p[TILE][4];
    __shared__ float predbuf[TILE][2];

    const int t    = threadIdx.x;
    const int lane = t & 63;
    const int wid  = t >> 6;     // 0..7
    const int wr   = wid >> 1;   // 0..3: rows wr*32 .. +32
    const int wc   = wid & 1;    // 0..1: cols wc*64 .. +64
    const int l15  = lane & 15;
    const int quad = lane >> 4;

    const float sig = sigma[0];
    const float q  = 0.7213475204444817f / (sig * sig);
    const float q2 = 2.0f * q;

    const bool regmode = (int)blockIdx.x >= nA;
    int rowbase;
    float rowterm[2][4];
    short8 a[8];   // A fragments, tile-invariant: a[i*4+kk], i in {0,1}

    if (!regmode) {
        rowbase = blockIdx.x * TILE;
        // stage X tile into fragment-layout LDS; each thread converts a
        // quarter-row (32 elems)
        const int r_  = t >> 2;
        const int qtr = t & 3;
        const int grow = rowbase + r_;
        unsigned short* dstbase = &ldsB[0][0] + (r_ >> 4) * 2048 + (r_ & 15) * 8;
        float ss = 0.f;
        if (grow < N) {
            const float4* src = (const float4*)(X + (size_t)grow * 128 + qtr * 32);
            #pragma unroll
            for (int c = 0; c < 4; ++c) {
                float4 va = src[2 * c], vb = src[2 * c + 1];
                unsigned short h0 = f32_to_bf16(va.x), h1 = f32_to_bf16(va.y);
                unsigned short h2 = f32_to_bf16(va.z), h3 = f32_to_bf16(va.w);
                unsigned short h4 = f32_to_bf16(vb.x), h5 = f32_to_bf16(vb.y);
                unsigned short h6 = f32_to_bf16(vb.z), h7 = f32_to_bf16(vb.w);
                float f0 = bf16_to_f32(h0), f1 = bf16_to_f32(h1);
                float f2 = bf16_to_f32(h2), f3 = bf16_to_f32(h3);
                float f4 = bf16_to_f32(h4), f5 = bf16_to_f32(h5);
                float f6 = bf16_to_f32(h6), f7 = bf16_to_f32(h7);
                ss = fmaf(f0, f0, ss); ss = fmaf(f1, f1, ss);
                ss = fmaf(f2, f2, ss); ss = fmaf(f3, f3, ss);
                ss = fmaf(f4, f4, ss); ss = fmaf(f5, f5, ss);
                ss = fmaf(f6, f6, ss); ss = fmaf(f7, f7, ss);
                uint4 pk;
                pk.x = (uint32_t)h0 | ((uint32_t)h1 << 16);
                pk.y = (uint32_t)h2 | ((uint32_t)h3 << 16);
                pk.z = (uint32_t)h4 | ((uint32_t)h5 << 16);
                pk.w = (uint32_t)h6 | ((uint32_t)h7 << 16);
                *reinterpret_cast<uint4*>(dstbase + (qtr * 4 + c) * 128) = pk;
            }
        } else {
            uint4 z; z.x = z.y = z.z = z.w = 0u;
            #pragma unroll
            for (int c = 0; c < 4; ++c)
                *reinterpret_cast<uint4*>(dstbase + (qtr * 4 + c) * 128) = z;
        }
        a2p[r_][qtr] = ss;
        __syncthreads();
        #pragma unroll
        for (int i = 0; i < 2; ++i)
            #pragma unroll
            for (int r = 0; r < 4; ++r) {
                int rl = wr * 32 + i * 16 + quad * 4 + r;
                rowterm[i][r] = (a2p[rl][0] + a2p[rl][1] + a2p[rl][2] + a2p[rl][3]) * q;
            }
        // hoist A fragments: 8 ds_read_b128, once for the whole kernel
        const unsigned short* aLds = &ldsB[0][0] + (size_t)(wr * 2) * 2048 + lane * 8;
        #pragma unroll
        for (int i = 0; i < 2; ++i)
            #pragma unroll
            for (int kk = 0; kk < 4; ++kk)
                a[i * 4 + kk] = *reinterpret_cast<const short8*>(aLds + (size_t)i * 2048 + kk * 512);
        __syncthreads();   // all waves done reading A from ldsB[0] before DMA overwrites
    } else {
        const int b2 = (int)blockIdx.x - nA;
        rowbase = b2 * TILE;
        const unsigned short* aG = Bp + (size_t)(b2 * 8 + wr * 2) * 2048 + lane * 8;
        #pragma unroll
        for (int i = 0; i < 2; ++i)
            #pragma unroll
            for (int kk = 0; kk < 4; ++kk)
                a[i * 4 + kk] = *reinterpret_cast<const short8*>(aG + (size_t)i * 2048 + kk * 512);
        #pragma unroll
        for (int i = 0; i < 2; ++i)
            #pragma unroll
            for (int r = 0; r < 4; ++r)
                rowterm[i][r] = cw[rowbase + wr * 32 + i * 16 + quad * 4 + r].x;
    }

    float srow[2][4] = {};
    const float2* cwb = cw + wc * 64 + l15;

    // this wave stages its 4 KB eighth of each tile: 4 x 1KB DMA issues
    const int ldq = wid * 2048 + lane * 8;   // element offset (shorts)

    // DMA tile 0 into ldsB[0]
    {
        const unsigned short* g = Bp + ldq;
        unsigned short* l = &ldsB[0][0] + ldq;
        #pragma unroll
        for (int k = 0; k < 4; ++k)
            dma16(g + k * 512, l + k * 512);
    }
    __syncthreads();   // vmcnt drain: tile 0 resident

    for (int mt = 0; mt < nMt; ++mt) {
        if (mt + 1 < nMt) {
            // fire-and-forget DMA of tile mt+1 into the other buffer;
            // drained by the barrier at the END of this iteration.
            const unsigned short* g = Bp + (size_t)(mt + 1) * 16384 + ldq;
            unsigned short* l = &ldsB[(mt + 1) & 1][0] + ldq;
            #pragma unroll
            for (int k = 0; k < 4; ++k)
                dma16(g + k * 512, l + k * 512);
        }

        // column constants for this tile (L2-hot; latency covered by TLP)
        float2 cj[4];
        #pragma unroll
        for (int j = 0; j < 4; ++j) cj[j] = cwb[(size_t)mt * 128 + j * 16];

        // compute tile mt from LDS: 4 column groups of 16, K=128 each
        const unsigned short* bfr = &ldsB[mt & 1][0] + (size_t)(wc * 4) * 2048 + lane * 8;
        #pragma unroll
        for (int j = 0; j < 4; ++j) {
            short8 b[4];
            #pragma unroll
            for (int kk = 0; kk < 4; ++kk)
                b[kk] = *reinterpret_cast<const short8*>(bfr + (size_t)j * 2048 + kk * 512);

            f32x4 acc4[2];
            #pragma unroll
            for (int i = 0; i < 2; ++i) acc4[i] = (f32x4){0.f, 0.f, 0.f, 0.f};
            #pragma unroll
            for (int kk = 0; kk < 4; ++kk)
                #pragma unroll
                for (int i = 0; i < 2; ++i)
                    acc4[i] = __builtin_amdgcn_mfma_f32_16x16x32_bf16(
                        a[i * 4 + kk], b[kk], acc4[i], 0, 0, 0);

            // epilogue: u = 2q*dot - (q*x2 + q*c2) <= ~0 ; srow += exp2(u)*alpha
            #pragma unroll
            for (int i = 0; i < 2; ++i) {
                #pragma unroll
                for (int r = 0; r < 4; ++r) {
                    float u = fmaf(acc4[i][r], q2, -(rowterm[i][r] + cj[j].x));
                    float e = __builtin_amdgcn_exp2f(u);
                    srow[i][r] = fmaf(e, cj[j].y, srow[i][r]);
                }
            }
        }

        __syncthreads();   // drains DMA(mt+1); all waves done reading buf[mt&1]
    }

    // reduce srow over the 16 lanes sharing a row
    #pragma unroll
    for (int i = 0; i < 2; ++i) {
        #pragma unroll
        for (int r = 0; r < 4; ++r) {
            int rl = wr * 32 + i * 16 + quad * 4 + r;
            float v = srow[i][r];
            v += __shfl_xor(v, 1);
            v += __shfl_xor(v, 2);
            v += __shfl_xor(v, 4);
            v += __shfl_xor(v, 8);
            if (l15 == 0)
                predbuf[rl][wc] = v;
        }
    }
    __syncthreads();

    float contrib = 0.f;
    if (t < TILE) {
        int grow = rowbase + t;
        if (!regmode) {
            if (grow < N) {
                float pred = predbuf[t][0] + predbuf[t][1];
                preds_out[grow] = pred;
                float d = pred - Yv[grow];
                contrib = d * d;
            }
        } else {
            float pred = predbuf[t][0] + predbuf[t][1];
            contrib = alpha[grow] * pred;
        }
    }
    contrib += __shfl_xor(contrib, 1);
    contrib += __shfl_xor(contrib, 2);
    contrib += __shfl_xor(contrib, 4);
    contrib += __shfl_xor(contrib, 8);
    contrib += __shfl_xor(contrib, 16);
    contrib += __shfl_xor(contrib, 32);
    if (lane == 0 && wid < 2) atomicAdd(regmode ? (acc + 1) : (acc + 0), contrib);

    __syncthreads();   // all waves' atomics drained before counting
    if (t == 0) {
        __threadfence();
        unsigned int old = atomicAdd((unsigned int*)(acc + 2), 1u);
        if (old == (unsigned int)(nBlk - 1)) {
            float lv = atomicAdd(acc + 0, 0.0f);   // coherent read-back
            float rv = atomicAdd(acc + 1, 0.0f);
            out0[0] = lv / (float)N + __expf(-penalty[0]) * rv;
        }
    }
}

extern "C" void kernel_launch(void* const* d_in, const int* in_sizes, int n_in,
                              void* d_out, int out_size, void* d_ws, size_t ws_size,
                              hipStream_t stream) {
    const float* X       = (const float*)d_in[0];
    const float* Y       = (const float*)d_in[1];
    const float* centers = (const float*)d_in[2];
    const float* alpha   = (const float*)d_in[3];
    const float* sigma   = (const float*)d_in[4];
    const float* penalty = (const float*)d_in[5];
    float* out = (float*)d_out;

    const int N = in_sizes[1];   // Y is [N,1]
    const int M = in_sizes[3];   // alpha is [M,1]

    unsigned short* Bp = (unsigned short*)d_ws;                 // M*128 bf16 = M*256 B
    float2* cw = (float2*)((char*)d_ws + (size_t)M * 256);      // M*8 B
    float* acc = (float*)((char*)d_ws + (size_t)M * 264);       // loss, reg, counter

    prep_kernel<<<M / 16, 256, 0, stream>>>(centers, alpha, sigma, Bp, cw, acc);

    const int nA  = (N + TILE - 1) / TILE;
    const int nMt = M / TILE;
    const int nBlk = nA + nMt;
    fused_kernel<<<nBlk, 512, 0, stream>>>(X, N, Y, Bp, cw, alpha, sigma, penalty,
                                           nA, nMt, nBlk, out + 1, out, acc);
}